// Round 7
// baseline (286.003 us; speedup 1.0000x reference)
//
#include <hip/hip_runtime.h>
#include <hip/hip_bf16.h>

#define B_ROWS 32768
#define L_DIM 512
#define H_DIM 1024
#define E_DIM 128
#define K_EXP 8
#define NBLK 128            // sort blocks: 32768/256
#define MAXT2 136           // max padded 256-row tiles
#define MAXB2 (MAXT2 * 256) // 34816

typedef __bf16 bf16x8 __attribute__((ext_vector_type(8)));
typedef float f32x4 __attribute__((ext_vector_type(4)));

__device__ __forceinline__ void gload16(const void* src, void* dst) {
    __builtin_amdgcn_global_load_lds(
        (const __attribute__((address_space(1))) unsigned int*)src,
        (__attribute__((address_space(3))) unsigned int*)dst, 16, 0, 0);
}

// meta: [0]=nT256 [1..9]=seg [10..18]=segP [19..26]=cnt [27..27+MAXT2)=texp (per 256-tile)
#define M_NT 0
#define M_SEG 1
#define M_SEGP 10
#define M_CNT 19
#define M_TEXP 27

// ---------------- sort: ids + per-block histogram ----------------
__global__ void k_ids_hist(const float* __restrict__ x, int* __restrict__ ids,
                           int* __restrict__ hist) {
    __shared__ int lh[K_EXP];
    int t = threadIdx.x;
    if (t < K_EXP) lh[t] = 0;
    __syncthreads();
    int i = blockIdx.x * 256 + t;
    int id = (int)x[(size_t)i * (L_DIM + 1) + L_DIM];
    ids[i] = id;
    atomicAdd(&lh[id], 1);
    __syncthreads();
    if (t < K_EXP) hist[blockIdx.x * K_EXP + t] = lh[t];
}

// ---------------- scan: 256-padded segments, tile->expert map ----------------
__global__ void k_scan(const int* __restrict__ hist, int* __restrict__ base,
                       int* __restrict__ meta, int* __restrict__ order_pad) {
    __shared__ int c[K_EXP];
    __shared__ int sp[K_EXP + 1];
    __shared__ int scnt[K_EXP];
    int k = threadIdx.x;  // 64 threads
    if (k < K_EXP) {
        int run = 0;
        for (int b = 0; b < NBLK; ++b) {
            base[b * K_EXP + k] = run;
            run += hist[b * K_EXP + k];
        }
        c[k] = run;
    }
    __syncthreads();
    if (k == 0) {
        int s = 0, p = 0;
        for (int e = 0; e < K_EXP; ++e) {
            meta[M_SEG + e] = s;
            meta[M_SEGP + e] = p;
            meta[M_CNT + e] = c[e];
            sp[e] = p;
            scnt[e] = c[e];
            s += c[e];
            p += ((c[e] + 255) >> 8) << 8;
        }
        meta[M_SEG + K_EXP] = s;
        meta[M_SEGP + K_EXP] = p;
        sp[K_EXP] = p;
        int nT = p >> 8;
        meta[M_NT] = nT;
        for (int e = 0; e < K_EXP; ++e)
            for (int t2 = sp[e] >> 8; t2 < (sp[e + 1] >> 8); ++t2)
                meta[M_TEXP + t2] = e;
        for (int t2 = nT; t2 < MAXT2; ++t2) meta[M_TEXP + t2] = 0;
    }
    __syncthreads();
    if (k < K_EXP) {
        int s0 = sp[k];
        for (int b = 0; b < NBLK; ++b) base[b * K_EXP + k] += s0;
    }
    for (int e = 0; e < K_EXP; ++e) {
        int st = sp[e] + scnt[e], en = sp[e + 1];
        for (int p2 = st + k; p2 < en; p2 += 64) order_pad[p2] = 0;
    }
    for (int p2 = sp[K_EXP] + k; p2 < MAXB2; p2 += 64) order_pad[p2] = 0;
}

// ---------------- stable order within block ----------------
__global__ void k_order(const int* __restrict__ ids, const int* __restrict__ base,
                        int* __restrict__ order) {
    __shared__ int sid[256];
    int t = threadIdx.x;
    int i = blockIdx.x * 256 + t;
    int my = ids[i];
    sid[t] = my;
    __syncthreads();
    int rank = 0;
    for (int j = 0; j < t; ++j) rank += (sid[j] == my) ? 1 : 0;
    order[base[blockIdx.x * K_EXP + my] + rank] = i;
}

// ---------------- gather sorted (padded) rows into packed bf16 xs ----------------
__global__ void k_gather(const float* __restrict__ x, const int* __restrict__ order,
                         __hip_bfloat16* __restrict__ xs) {
    int idx = blockIdx.x * 256 + threadIdx.x;
    int p = idx >> 7;
    int c4 = (idx & 127) << 2;
    int src = order[p];
    const float* sp = x + (size_t)src * (L_DIM + 1) + c4;
    __hip_bfloat16 v[4];
    v[0] = __float2bfloat16(sp[0]);
    v[1] = __float2bfloat16(sp[1]);
    v[2] = __float2bfloat16(sp[2]);
    v[3] = __float2bfloat16(sp[3]);
    *(uint2*)(xs + (size_t)p * L_DIM + c4) = *(uint2*)v;
}

__global__ void k_transpose(const float* __restrict__ W, __hip_bfloat16* __restrict__ Wt,
                            int KDim, int NDim) {
    __shared__ float tile[32][33];
    int k0 = blockIdx.x << 5, n0 = blockIdx.y << 5;
    const float* Wb = W + (size_t)blockIdx.z * KDim * NDim;
    __hip_bfloat16* Wtb = Wt + (size_t)blockIdx.z * KDim * NDim;
    int tx = threadIdx.x & 31, ty = threadIdx.x >> 5;
    for (int i = ty; i < 32; i += 8)
        tile[i][tx] = Wb[(size_t)(k0 + i) * NDim + n0 + tx];
    __syncthreads();
    for (int i = ty; i < 32; i += 8)
        Wtb[(size_t)(n0 + i) * KDim + k0 + tx] = __float2bfloat16(tile[tx][i]);
}

// ---------------- 256x256 8-phase MFMA GEMM (T2+T3+T4+T5) ----------------
// BK=64, 512 threads = 8 waves (2M x 4N), per-wave 128x64 (8x4 frags).
// LDS 128KB: 2 dbuf x (A 256x64 + B 256x64). Stage by half-tiles; each stage
// targets a region whose last ds_read was in a PRIOR phase (barrier-protected).
// vmcnt(4) gates only at phase 4/8 closing barriers. 8-slot XOR swizzle.
#define BARRIER asm volatile("s_barrier" ::: "memory")
#define LGKM0   asm volatile("s_waitcnt lgkmcnt(0)" ::: "memory")
#define VM4BAR  asm volatile("s_waitcnt vmcnt(4)\ns_barrier" ::: "memory")
#define VM0BAR  asm volatile("s_waitcnt vmcnt(0)\ns_barrier" ::: "memory")

template <int KD, int ND, bool GROUPED, bool LEAKY, bool OUT_BF16, bool MAPROW>
__launch_bounds__(512, 2)
__global__ void gemm8(const __hip_bfloat16* __restrict__ A,
                      const __hip_bfloat16* __restrict__ Bt,
                      const float* __restrict__ bias,
                      void* __restrict__ Cout,
                      const int* __restrict__ meta) {
    constexpr int NNT = ND / 256;
    constexpr int TOT = MAXT2 * NNT;
    static_assert(TOT % 8 == 0, "XCD chunking");
    constexpr int NKT = KD / 64;
    constexpr int NI = NKT / 2;
    static_assert(NKT % 2 == 0, "even K-tiles");
    constexpr int DBUF = 32768;  // elems per dbuf: A 16384 + B 16384

    __shared__ __align__(16) __hip_bfloat16 smem[2 * DBUF];  // 128 KB

    const int id = blockIdx.x;
    const int wg = (id & 7) * (TOT / 8) + (id >> 3);
    const int mt = wg / NNT, nt = wg % NNT;
    const int m0 = mt << 8, n0 = nt << 8;
    const __hip_bfloat16* Bp = Bt;
    const float* bp = bias;
    int e = 0;
    if (GROUPED) {
        e = meta[M_TEXP + mt];
        Bp += (size_t)e * KD * ND;
        bp += (size_t)e * ND;
    }
    const int t = threadIdx.x;
    const int w = t >> 6, l = t & 63;
    const int wm = w >> 2, wn = w & 3;
    const int g = l >> 4, li = l & 15;
    const int sr = l >> 3, sc = l & 7;  // stage: row-sub, linear slot

    f32x4 acc[8][4];
#pragma unroll
    for (int i = 0; i < 8; ++i)
#pragma unroll
        for (int j = 0; j < 4; ++j) acc[i][j] = (f32x4){0.f, 0.f, 0.f, 0.f};

    // stage one half-tile (128 rows x 64 k): 2 gloads/thread, linear LDS dest,
    // inverse-swizzled global source (src k16 = kt*8 + (slot ^ row&7)).
    auto stageH = [&](int d, int which, int half, int kt) {
        const __hip_bfloat16* src = which ? Bp : A;
        const int rb = (which ? n0 : m0) + half * 128;
#pragma unroll
        for (int q = 0; q < 2; ++q) {
            int rl = (q * 8 + w) * 8;  // 8-row group (wave-uniform)
            gload16(src + (size_t)(rb + rl + sr) * KD + (size_t)(kt * 8 + (sc ^ sr)) * 8,
                    &smem[d * DBUF + which * 16384 + half * 8192 + rl * 64]);
        }
    };

    bf16x8 a0[8], a1[8], bb[2];
    auto LDA = [&](int d, int ksub, bf16x8* ar) {
#pragma unroll
        for (int fm = 0; fm < 8; ++fm) {
            int r = wm * 128 + fm * 16 + li;
            ar[fm] = *(const bf16x8*)&smem[d * DBUF + r * 64 + (((ksub << 2) + g) ^ (r & 7)) * 8];
        }
    };
    auto LDB = [&](int d, int np, int ksub) {
#pragma unroll
        for (int j = 0; j < 2; ++j) {
            int r = wn * 64 + (np * 2 + j) * 16 + li;
            bb[j] = *(const bf16x8*)&smem[d * DBUF + 16384 + r * 64 + (((ksub << 2) + g) ^ (r & 7)) * 8];
        }
    };
    auto MM = [&](int np, bf16x8* ar) {
        __builtin_amdgcn_s_setprio(1);
#pragma unroll
        for (int fm = 0; fm < 8; ++fm) {
            acc[fm][np * 2 + 0] = __builtin_amdgcn_mfma_f32_16x16x32_bf16(
                ar[fm], bb[0], acc[fm][np * 2 + 0], 0, 0, 0);
            acc[fm][np * 2 + 1] = __builtin_amdgcn_mfma_f32_16x16x32_bf16(
                ar[fm], bb[1], acc[fm][np * 2 + 1], 0, 0, 0);
        }
        __builtin_amdgcn_s_setprio(0);
    };

    // prologue: tile0 A+B -> dbuf0; tile1 A -> dbuf1; wait tile0 landed
    stageH(0, 0, 0, 0); stageH(0, 0, 1, 0);
    stageH(0, 1, 0, 0); stageH(0, 1, 1, 0);
    stageH(1, 0, 0, 1); stageH(1, 0, 1, 1);
    VM4BAR;
    __builtin_amdgcn_sched_barrier(0);

    for (int i = 0; i < NI; ++i) {
        const int E2 = 2 * i + 2, O1 = 2 * i + 1, O2 = 2 * i + 3;
        const bool more = (i + 1 < NI);
        // ph1: even tile, np0 k0; stage B-half0(odd)->dbuf1 (B dbuf1 last read prev ph8)
        LDA(0, 0, a0); LDB(0, 0, 0); stageH(1, 1, 0, O1);
        BARRIER; LGKM0; MM(0, a0); BARRIER;
        // ph2: np0 k1; stage B-half1(odd)
        LDA(0, 1, a1); LDB(0, 0, 1); stageH(1, 1, 1, O1);
        BARRIER; LGKM0; MM(0, a1); BARRIER;
        // ph3: np1 k0 (A regs reused); stage A-half0(next even)->dbuf0 (A dbuf0 done at ph2)
        LDB(0, 1, 0); if (more) stageH(0, 0, 0, E2);
        BARRIER; LGKM0; MM(1, a0); BARRIER;
        // ph4: np1 k1; stage A-half1(next even); GATE: odd tile fully resident
        LDB(0, 1, 1); if (more) stageH(0, 0, 1, E2);
        BARRIER; LGKM0; MM(1, a1);
        if (more) { VM4BAR; } else { VM0BAR; }
        __builtin_amdgcn_sched_barrier(0);
        // ph5: odd tile, np0 k0; stage B-half0(next even)->dbuf0 (B dbuf0 done at ph4)
        LDA(1, 0, a0); LDB(1, 0, 0); if (more) stageH(0, 1, 0, E2);
        BARRIER; LGKM0; MM(0, a0); BARRIER;
        // ph6: np0 k1; stage B-half1(next even)
        LDA(1, 1, a1); LDB(1, 0, 1); if (more) stageH(0, 1, 1, E2);
        BARRIER; LGKM0; MM(0, a1); BARRIER;
        // ph7: np1 k0; stage A-half0(next odd)->dbuf1 (A dbuf1 done at ph6)
        LDB(1, 1, 0); if (more) stageH(1, 0, 0, O2);
        BARRIER; LGKM0; MM(1, a0); BARRIER;
        // ph8: np1 k1; stage A-half1(next odd); GATE: next even tile resident
        LDB(1, 1, 1); if (more) stageH(1, 0, 1, O2);
        BARRIER; LGKM0; MM(1, a1);
        if (more) { VM4BAR; __builtin_amdgcn_sched_barrier(0); }
    }

    // epilogue: C/D layout col=lane&15, row=(lane>>4)*4+reg
    float bv[4];
#pragma unroll
    for (int fn = 0; fn < 4; ++fn) bv[fn] = bp[n0 + wn * 64 + fn * 16 + li];
    int se = 0, sp2 = 0, ce = 0;
    if (MAPROW) { se = meta[M_SEG + e]; sp2 = meta[M_SEGP + e]; ce = meta[M_CNT + e]; }
#pragma unroll
    for (int fm = 0; fm < 8; ++fm)
#pragma unroll
        for (int ii = 0; ii < 4; ++ii) {
            int rp = m0 + wm * 128 + fm * 16 + g * 4 + ii;
#pragma unroll
            for (int fn = 0; fn < 4; ++fn) {
                float v = acc[fm][fn][ii] + bv[fn];
                if (LEAKY) v = v > 0.f ? v : 0.01f * v;
                int col = n0 + wn * 64 + fn * 16 + li;
                if (MAPROW) {
                    int local = rp - sp2;
                    if (local < ce)
                        ((float*)Cout)[(size_t)(se + local) * ND + col] = v;
                } else if (OUT_BF16) {
                    ((__hip_bfloat16*)Cout)[(size_t)rp * ND + col] = __float2bfloat16(v);
                } else {
                    ((float*)Cout)[(size_t)rp * ND + col] = v;
                }
            }
        }
}

// ---------------- ring-3 128x128 kernel for G3 (K=128, meta-grouped) ----------------
template <int ND, bool LEAKY>
__launch_bounds__(256)
__global__ void gemm_g3(const __hip_bfloat16* __restrict__ A,
                        const __hip_bfloat16* __restrict__ Bt,
                        const float* __restrict__ bias,
                        __hip_bfloat16* __restrict__ Cout,
                        const int* __restrict__ meta) {
    constexpr int KD = 128;
    constexpr int NNT = ND / 128;
    constexpr int TOT = (MAXB2 / 128) * NNT;
    static_assert(TOT % 8 == 0, "XCD chunking");
    constexpr int SLOT = 2 * 128 * 32;  // A + B elems per ring slot
    constexpr int NK = KD / 32;
    __shared__ __align__(16) __hip_bfloat16 smem[3 * SLOT];
    const int id = blockIdx.x;
    const int wg = (id & 7) * (TOT / 8) + (id >> 3);
    const int mt = wg / NNT, nt = wg % NNT;
    const int e = meta[M_TEXP + (mt >> 1)];
    const int m0 = mt << 7, n0 = nt << 7;
    const __hip_bfloat16* Bp = Bt + (size_t)e * KD * ND;
    const float* bp = bias + (size_t)e * ND;
    const int t = threadIdx.x, w = t >> 6, l = t & 63;
    const int wm = w >> 1, wn = w & 1, g = l >> 4, li = l & 15;
    const int q0 = 2 * w, r0 = l >> 2, s0 = l & 3;

    f32x4 acc[4][4];
#pragma unroll
    for (int i = 0; i < 4; ++i)
#pragma unroll
        for (int j = 0; j < 4; ++j) acc[i][j] = (f32x4){0.f, 0.f, 0.f, 0.f};

    auto stage = [&](int b, int kt) {
#pragma unroll
        for (int qi = 0; qi < 2; ++qi) {
            int q = q0 + qi, r = q * 16 + r0;
            int ksg = s0 ^ ((r >> 1) & 3);
            gload16(A + (size_t)(m0 + r) * KD + kt * 32 + ksg * 8,
                    &smem[b * SLOT + q * 512]);
        }
#pragma unroll
        for (int qi = 0; qi < 2; ++qi) {
            int q = q0 + qi, r = q * 16 + r0;
            int ksg = s0 ^ ((r >> 1) & 3);
            gload16(Bp + (size_t)(n0 + r) * KD + kt * 32 + ksg * 8,
                    &smem[b * SLOT + 4096 + q * 512]);
        }
    };

    stage(0, 0);
    stage(1, 1);
    int b = 0;
    for (int kt = 0; kt < NK; ++kt) {
        if (kt == NK - 1) { VM0BAR; } else { VM4BAR; }
        __builtin_amdgcn_sched_barrier(0);
        if (kt + 2 < NK) stage((b + 2 >= 3) ? b - 1 : b + 2, kt + 2);
        bf16x8 af[4], bfr[4];
#pragma unroll
        for (int fm = 0; fm < 4; ++fm) {
            int rr = wm * 64 + fm * 16 + li;
            int ss = g ^ ((rr >> 1) & 3);
            af[fm] = *(const bf16x8*)&smem[b * SLOT + rr * 32 + ss * 8];
        }
#pragma unroll
        for (int fn = 0; fn < 4; ++fn) {
            int cc = wn * 64 + fn * 16 + li;
            int ss = g ^ ((cc >> 1) & 3);
            bfr[fn] = *(const bf16x8*)&smem[b * SLOT + 4096 + cc * 32 + ss * 8];
        }
        __builtin_amdgcn_s_setprio(1);
#pragma unroll
        for (int fm = 0; fm < 4; ++fm)
#pragma unroll
            for (int fn = 0; fn < 4; ++fn)
                acc[fm][fn] = __builtin_amdgcn_mfma_f32_16x16x32_bf16(
                    af[fm], bfr[fn], acc[fm][fn], 0, 0, 0);
        __builtin_amdgcn_s_setprio(0);
        b = (b + 1 >= 3) ? 0 : b + 1;
    }

    float bv[4];
#pragma unroll
    for (int fn = 0; fn < 4; ++fn) bv[fn] = bp[n0 + wn * 64 + fn * 16 + li];
#pragma unroll
    for (int fm = 0; fm < 4; ++fm)
#pragma unroll
        for (int i = 0; i < 4; ++i) {
            int r = m0 + wm * 64 + fm * 16 + g * 4 + i;
#pragma unroll
            for (int fn = 0; fn < 4; ++fn) {
                float v = acc[fm][fn][i] + bv[fn];
                if (LEAKY) v = v > 0.f ? v : 0.01f * v;
                Cout[(size_t)r * ND + n0 + wn * 64 + fn * 16 + li] = __float2bfloat16(v);
            }
        }
}

// ---------------- BM=64 ring-3 kernel for G2 (dense, N=128) ----------------
template <int KD, int ND, bool LEAKY>
__launch_bounds__(256)
__global__ void gemm_u64(const __hip_bfloat16* __restrict__ A,
                         const __hip_bfloat16* __restrict__ Bt,
                         const float* __restrict__ bias,
                         __hip_bfloat16* __restrict__ Cout) {
    constexpr int BM = 64;
    constexpr int NNT = ND / 128;
    constexpr int NMT = MAXB2 / BM;
    constexpr int TOT = NMT * NNT;
    static_assert(TOT % 8 == 0, "XCD chunking");
    constexpr int ACH = BM * 32;
    constexpr int SLOT = ACH + 128 * 32;
    constexpr int NK = KD / 32;

    __shared__ __align__(16) __hip_bfloat16 smem[3 * SLOT];
    const int id = blockIdx.x;
    const int wg = (id & 7) * (TOT / 8) + (id >> 3);
    const int mt = wg / NNT, nt = wg % NNT;
    const int n0 = nt << 7;
    const int m0 = mt * BM;
    const int t = threadIdx.x, w = t >> 6, l = t & 63;
    const int wm = w >> 1, wn = w & 1, g = l >> 4, li = l & 15;
    const int r0 = l >> 2, s0 = l & 3;

    f32x4 acc[2][4];
#pragma unroll
    for (int i = 0; i < 2; ++i)
#pragma unroll
        for (int j = 0; j < 4; ++j) acc[i][j] = (f32x4){0.f, 0.f, 0.f, 0.f};

    auto stage = [&](int b, int kt) {
        {
            int q = w, r = q * 16 + r0;
            int ksg = s0 ^ ((r >> 1) & 3);
            gload16(A + (size_t)(m0 + r) * KD + kt * 32 + ksg * 8,
                    &smem[b * SLOT + q * 512]);
        }
#pragma unroll
        for (int qi = 0; qi < 2; ++qi) {
            int q = 2 * w + qi, r = q * 16 + r0;
            int ksg = s0 ^ ((r >> 1) & 3);
            gload16(Bt + (size_t)(n0 + r) * KD + kt * 32 + ksg * 8,
                    &smem[b * SLOT + ACH + q * 512]);
        }
    };

    stage(0, 0);
    stage(1, 1);
    int b = 0;
    for (int kt = 0; kt < NK; ++kt) {
        if (kt == NK - 1)
            asm volatile("s_waitcnt vmcnt(0)\ns_barrier" ::: "memory");
        else
            asm volatile("s_waitcnt vmcnt(3)\ns_barrier" ::: "memory");
        __builtin_amdgcn_sched_barrier(0);
        if (kt + 2 < NK) stage((b + 2 >= 3) ? b - 1 : b + 2, kt + 2);
        bf16x8 af[2], bfr[4];
#pragma unroll
        for (int fm = 0; fm < 2; ++fm) {
            int rr = wm * 32 + fm * 16 + li;
            int ss = g ^ ((rr >> 1) & 3);
            af[fm] = *(const bf16x8*)&smem[b * SLOT + rr * 32 + ss * 8];
        }
#pragma unroll
        for (int fn = 0; fn < 4; ++fn) {
            int cc = wn * 64 + fn * 16 + li;
            int ss = g ^ ((cc >> 1) & 3);
            bfr[fn] = *(const bf16x8*)&smem[b * SLOT + ACH + cc * 32 + ss * 8];
        }
        __builtin_amdgcn_s_setprio(1);
#pragma unroll
        for (int fm = 0; fm < 2; ++fm)
#pragma unroll
            for (int fn = 0; fn < 4; ++fn)
                acc[fm][fn] = __builtin_amdgcn_mfma_f32_16x16x32_bf16(
                    af[fm], bfr[fn], acc[fm][fn], 0, 0, 0);
        __builtin_amdgcn_s_setprio(0);
        b = (b + 1 >= 3) ? 0 : b + 1;
    }

    float bv[4];
#pragma unroll
    for (int fn = 0; fn < 4; ++fn) bv[fn] = bias[n0 + wn * 64 + fn * 16 + li];
#pragma unroll
    for (int fm = 0; fm < 2; ++fm)
#pragma unroll
        for (int i = 0; i < 4; ++i) {
            int r = m0 + wm * 32 + fm * 16 + g * 4 + i;
#pragma unroll
            for (int fn = 0; fn < 4; ++fn) {
                float v = acc[fm][fn][i] + bv[fn];
                if (LEAKY) v = v > 0.f ? v : 0.01f * v;
                Cout[(size_t)r * ND + n0 + wn * 64 + fn * 16 + li] = __float2bfloat16(v);
            }
        }
}

extern "C" void kernel_launch(void* const* d_in, const int* in_sizes, int n_in,
                              void* d_out, int out_size, void* d_ws, size_t ws_size,
                              hipStream_t stream) {
    (void)in_sizes; (void)n_in; (void)out_size; (void)ws_size;
    const float* x   = (const float*)d_in[0];
    const float* We1 = (const float*)d_in[1];
    const float* be1 = (const float*)d_in[2];
    const float* We2 = (const float*)d_in[3];
    const float* be2 = (const float*)d_in[4];
    const float* Wd1 = (const float*)d_in[5];
    const float* bd1 = (const float*)d_in[6];
    const float* Wd2 = (const float*)d_in[7];
    const float* bd2 = (const float*)d_in[8];
    float* out = (float*)d_out;

    char* w = (char*)d_ws;
    auto alloc = [&](size_t bytes) {
        char* p = w;
        w += (bytes + 255) & ~(size_t)255;
        return p;
    };
    int* ids       = (int*)alloc((size_t)B_ROWS * 4);
    int* order_pad = (int*)alloc((size_t)MAXB2 * 4);
    int* hist      = (int*)alloc((size_t)NBLK * K_EXP * 4);
    int* base      = (int*)alloc((size_t)NBLK * K_EXP * 4);
    int* meta      = (int*)alloc((size_t)(M_TEXP + MAXT2) * 4);
    __hip_bfloat16* xs   = (__hip_bfloat16*)alloc((size_t)MAXB2 * L_DIM * 2);   // 35.7 MB
    __hip_bfloat16* hbuf = (__hip_bfloat16*)alloc((size_t)MAXB2 * H_DIM * 2);   // 71.3 MB (h, then hd)
    __hip_bfloat16* zbuf = (__hip_bfloat16*)alloc((size_t)MAXB2 * E_DIM * 2);   // 8.9 MB
    __hip_bfloat16* Wt1  = (__hip_bfloat16*)alloc((size_t)L_DIM * H_DIM * 2);
    __hip_bfloat16* Wt2  = (__hip_bfloat16*)alloc((size_t)H_DIM * E_DIM * 2);
    __hip_bfloat16* Wd1t = (__hip_bfloat16*)alloc((size_t)K_EXP * E_DIM * H_DIM * 2);
    __hip_bfloat16* Wd2t = (__hip_bfloat16*)alloc((size_t)K_EXP * H_DIM * L_DIM * 2);

    k_ids_hist<<<NBLK, 256, 0, stream>>>(x, ids, hist);
    k_scan<<<1, 64, 0, stream>>>(hist, base, meta, order_pad);
    k_order<<<NBLK, 256, 0, stream>>>(ids, base, order_pad);
    k_gather<<<(MAXB2 * (L_DIM / 4)) / 256, 256, 0, stream>>>(x, order_pad, xs);

    k_transpose<<<dim3(L_DIM / 32, H_DIM / 32, 1), 256, 0, stream>>>(We1, Wt1, L_DIM, H_DIM);
    k_transpose<<<dim3(H_DIM / 32, E_DIM / 32, 1), 256, 0, stream>>>(We2, Wt2, H_DIM, E_DIM);
    k_transpose<<<dim3(E_DIM / 32, H_DIM / 32, K_EXP), 256, 0, stream>>>(Wd1, Wd1t, E_DIM, H_DIM);
    k_transpose<<<dim3(H_DIM / 32, L_DIM / 32, K_EXP), 256, 0, stream>>>(Wd2, Wd2t, H_DIM, L_DIM);

    // G1: h = leaky(xs @ We1 + be1)    [MAXB2,512]@[512,1024], 8-phase 256^2
    gemm8<L_DIM, H_DIM, false, true, true, false>
        <<<MAXT2 * (H_DIM / 256), 512, 0, stream>>>(xs, Wt1, be1, hbuf, meta);
    // G2: z = leaky(h @ We2 + be2)     [MAXB2,1024]@[1024,128], BM=64 ring-3
    gemm_u64<H_DIM, E_DIM, true>
        <<<(MAXB2 / 64) * (E_DIM / 128), 256, 0, stream>>>(hbuf, Wt2, be2, zbuf);
    // G3: hd = leaky(z @ Wd1[e] + bd1[e])  grouped, ring-3 128^2 (K=128)
    gemm_g3<H_DIM, true>
        <<<(MAXB2 / 128) * (H_DIM / 128), 256, 0, stream>>>(zbuf, Wd1t, bd1, hbuf, meta);
    // G4: out = hd @ Wd2[e] + bd2[e]   grouped 8-phase 256^2, fp32 out, padded->sorted rows
    gemm8<H_DIM, L_DIM, true, false, false, true>
        <<<MAXT2 * (L_DIM / 256), 512, 0, stream>>>(hbuf, Wd2t, bd2, out, meta);
}

// Round 8
// 201.495 us; speedup vs baseline: 1.4194x; 1.4194x over previous
//
#include <hip/hip_runtime.h>
#include <hip/hip_bf16.h>

#define B_ROWS 32768
#define L_DIM 512
#define H_DIM 1024
#define E_DIM 128
#define K_EXP 8
#define NBLK 128   // sort blocks: 32768/256

typedef __bf16 bf16x8 __attribute__((ext_vector_type(8)));
typedef float f32x4 __attribute__((ext_vector_type(4)));

__device__ __forceinline__ void gload16(const void* src, void* dst) {
    __builtin_amdgcn_global_load_lds(
        (const __attribute__((address_space(1))) unsigned int*)src,
        (__attribute__((address_space(3))) unsigned int*)dst, 16, 0, 0);
}

// ---------------- sort: ids + per-block histogram ----------------
__global__ void k_ids_hist(const float* __restrict__ x, int* __restrict__ ids,
                           int* __restrict__ hist) {
    __shared__ int lh[K_EXP];
    int t = threadIdx.x;
    if (t < K_EXP) lh[t] = 0;
    __syncthreads();
    int i = blockIdx.x * 256 + t;
    int id = (int)x[(size_t)i * (L_DIM + 1) + L_DIM];
    ids[i] = id;
    atomicAdd(&lh[id], 1);
    __syncthreads();
    if (t < K_EXP) hist[blockIdx.x * K_EXP + t] = lh[t];
}

__global__ void k_scan(const int* __restrict__ hist, int* __restrict__ base,
                       int* __restrict__ seg, int* __restrict__ tp) {
    __shared__ int c[K_EXP];
    __shared__ int sseg[K_EXP + 1];
    int k = threadIdx.x;
    if (k < K_EXP) {
        int run = 0;
        for (int b = 0; b < NBLK; ++b) {
            base[b * K_EXP + k] = run;
            run += hist[b * K_EXP + k];
        }
        c[k] = run;
    }
    __syncthreads();
    if (k == 0) {
        int s = 0, t2 = 0;
        for (int e = 0; e < K_EXP; ++e) {
            sseg[e] = s; seg[e] = s; tp[e] = t2;
            s += c[e]; t2 += (c[e] + 127) >> 7;
        }
        sseg[K_EXP] = s; seg[K_EXP] = s; tp[K_EXP] = t2;
    }
    __syncthreads();
    if (k < K_EXP) {
        int s0 = sseg[k];
        for (int b = 0; b < NBLK; ++b) base[b * K_EXP + k] += s0;
    }
}

__global__ void k_order(const int* __restrict__ ids, const int* __restrict__ base,
                        int* __restrict__ order) {
    __shared__ int sid[256];
    int t = threadIdx.x;
    int i = blockIdx.x * 256 + t;
    int my = ids[i];
    sid[t] = my;
    __syncthreads();
    int rank = 0;
    for (int j = 0; j < t; ++j) rank += (sid[j] == my) ? 1 : 0;
    order[base[blockIdx.x * K_EXP + my] + rank] = i;
}

__global__ void k_gather(const float* __restrict__ x, const int* __restrict__ order,
                         __hip_bfloat16* __restrict__ xs) {
    int idx = blockIdx.x * 256 + threadIdx.x;
    int p = idx >> 7;
    int c4 = (idx & 127) << 2;
    int src = order[p];
    const float* sp = x + (size_t)src * (L_DIM + 1) + c4;
    __hip_bfloat16 v[4];
    v[0] = __float2bfloat16(sp[0]);
    v[1] = __float2bfloat16(sp[1]);
    v[2] = __float2bfloat16(sp[2]);
    v[3] = __float2bfloat16(sp[3]);
    *(uint2*)(xs + (size_t)p * L_DIM + c4) = *(uint2*)v;
}

// ---------------- fused weight transpose + fp32->bf16 (all 4 weights, 1 launch) ----------------
// grid: 512 (We1) + 128 (We2) + 1024 (Wd1 x8) + 4096 (Wd2 x8) = 5760 blocks of 256
__global__ void k_wtrans(const float* __restrict__ We1, const float* __restrict__ We2,
                         const float* __restrict__ Wd1, const float* __restrict__ Wd2,
                         __hip_bfloat16* __restrict__ Wt1, __hip_bfloat16* __restrict__ Wt2,
                         __hip_bfloat16* __restrict__ Wd1t, __hip_bfloat16* __restrict__ Wd2t) {
    __shared__ float tile[32][33];
    int b = blockIdx.x;
    const float* W;
    __hip_bfloat16* Wt;
    int KDim, NDim, local;
    if (b < 512)       { W = We1; Wt = Wt1; KDim = 512;  NDim = 1024; local = b; }
    else if (b < 640)  { W = We2; Wt = Wt2; KDim = 1024; NDim = 128;  local = b - 512; }
    else if (b < 1664) {
        int lb = b - 640;
        int e = lb >> 7;            // 128 tiles per expert (4 k x 32 n)
        local = lb & 127;
        KDim = 128; NDim = 1024;
        W = Wd1 + (size_t)e * KDim * NDim;
        Wt = Wd1t + (size_t)e * KDim * NDim;
    } else {
        int lb = b - 1664;
        int e = lb >> 9;            // 512 tiles per expert (32 k x 16 n)
        local = lb & 511;
        KDim = 1024; NDim = 512;
        W = Wd2 + (size_t)e * KDim * NDim;
        Wt = Wd2t + (size_t)e * KDim * NDim;
    }
    int ntK = KDim >> 5;
    int k0 = (local % ntK) << 5, n0 = (local / ntK) << 5;
    int tx = threadIdx.x & 31, ty = threadIdx.x >> 5;
    for (int i = ty; i < 32; i += 8)
        tile[i][tx] = W[(size_t)(k0 + i) * NDim + n0 + tx];
    __syncthreads();
    for (int i = ty; i < 32; i += 8)
        Wt[(size_t)(n0 + i) * KDim + k0 + tx] = __float2bfloat16(tile[tx][i]);
}

// ---------------- ring-3 MFMA GEMM body (R5-proven) ----------------
// C[M,N] = epi(A[M,KD] @ Bt[N,KD]^T + bias); BM x 128 tile, BK=32, 4 waves.
// 1D grid, n-fastest + bijective XCD chunking; 3 LDS ring slots; stage t+2
// while computing t; gate s_waitcnt vmcnt(loads-per-stage) + s_barrier.
template <int BM, int KD, int ND, bool GROUPED, bool LEAKY, bool OUT_BF16>
__device__ __forceinline__ void gemm_body(__hip_bfloat16* smem,
                                          const __hip_bfloat16* __restrict__ A,
                                          const __hip_bfloat16* __restrict__ Bt,
                                          const float* __restrict__ bias,
                                          void* __restrict__ Cout,
                                          const int* __restrict__ seg,
                                          const int* __restrict__ tp) {
    constexpr int NNT = ND / 128;
    constexpr int NMT = GROUPED ? (B_ROWS / 128 + K_EXP) : (B_ROWS / BM);
    constexpr int TOT = NMT * NNT;
    static_assert(TOT % 8 == 0, "XCD chunking needs TOT % 8 == 0");
    constexpr int ACH = BM * 32;
    constexpr int SLOT = ACH + 128 * 32;
    constexpr int NK = KD / 32;
    constexpr int VG = (BM == 128) ? 4 : 3;

    const int id = blockIdx.x;
    const int wg = (id & 7) * (TOT / 8) + (id >> 3);
    const int mt = wg / NNT, nt = wg % NNT;
    const int n0 = nt << 7;
    int m0, mEnd;
    const __hip_bfloat16* Bp = Bt;
    const float* bp = bias;
    if (GROUPED) {
        if (mt >= tp[K_EXP]) return;
        int e = 0;
        while (mt >= tp[e + 1]) ++e;
        m0 = seg[e] + ((mt - tp[e]) << 7);
        mEnd = seg[e + 1];
        Bp += (size_t)e * KD * ND;
        bp += (size_t)e * ND;
    } else {
        m0 = mt * BM;
        mEnd = m0 + BM;
    }
    const int t = threadIdx.x, w = t >> 6, l = t & 63;
    constexpr int FM = BM / 32;
    const int wm = w >> 1, wn = w & 1, g = l >> 4, li = l & 15;
    const int r0 = l >> 2, s0 = l & 3;

    f32x4 acc[FM][4];
#pragma unroll
    for (int i = 0; i < FM; ++i)
#pragma unroll
        for (int j = 0; j < 4; ++j) acc[i][j] = (f32x4){0.f, 0.f, 0.f, 0.f};

    auto stage = [&](int b, int kt) {
#pragma unroll
        for (int qi = 0; qi < BM / 64; ++qi) {
            int q = (BM / 64) * w + qi;
            int r = q * 16 + r0;
            int ksg = s0 ^ ((r >> 1) & 3);
            int rowg = m0 + r;
            if (GROUPED) rowg = min(rowg, B_ROWS - 1);
            gload16(A + (size_t)rowg * KD + kt * 32 + ksg * 8,
                    &smem[b * SLOT + q * 512]);
        }
#pragma unroll
        for (int qi = 0; qi < 2; ++qi) {
            int q = 2 * w + qi;
            int r = q * 16 + r0;
            int ksg = s0 ^ ((r >> 1) & 3);
            gload16(Bp + (size_t)(n0 + r) * KD + kt * 32 + ksg * 8,
                    &smem[b * SLOT + ACH + q * 512]);
        }
    };

    stage(0, 0);
    stage(1, 1);
    int b = 0;
    for (int kt = 0; kt < NK; ++kt) {
        if (kt == NK - 1)
            asm volatile("s_waitcnt vmcnt(0)\ns_barrier" ::: "memory");
        else if constexpr (VG == 4)
            asm volatile("s_waitcnt vmcnt(4)\ns_barrier" ::: "memory");
        else
            asm volatile("s_waitcnt vmcnt(3)\ns_barrier" ::: "memory");
        __builtin_amdgcn_sched_barrier(0);
        if (kt + 2 < NK) stage((b + 2 >= 3) ? b - 1 : b + 2, kt + 2);
        bf16x8 af[FM], bfr[4];
#pragma unroll
        for (int fm = 0; fm < FM; ++fm) {
            int rr = wm * (FM * 16) + fm * 16 + li;
            int ss = g ^ ((rr >> 1) & 3);
            af[fm] = *(const bf16x8*)&smem[b * SLOT + rr * 32 + ss * 8];
        }
#pragma unroll
        for (int fn = 0; fn < 4; ++fn) {
            int cc = wn * 64 + fn * 16 + li;
            int ss = g ^ ((cc >> 1) & 3);
            bfr[fn] = *(const bf16x8*)&smem[b * SLOT + ACH + cc * 32 + ss * 8];
        }
        __builtin_amdgcn_s_setprio(1);
#pragma unroll
        for (int fm = 0; fm < FM; ++fm)
#pragma unroll
            for (int fn = 0; fn < 4; ++fn)
                acc[fm][fn] = __builtin_amdgcn_mfma_f32_16x16x32_bf16(
                    af[fm], bfr[fn], acc[fm][fn], 0, 0, 0);
        __builtin_amdgcn_s_setprio(0);
        b = (b + 1 >= 3) ? 0 : b + 1;
    }

    float bv[4];
#pragma unroll
    for (int fn = 0; fn < 4; ++fn) bv[fn] = bp[n0 + wn * 64 + fn * 16 + li];
#pragma unroll
    for (int fm = 0; fm < FM; ++fm)
#pragma unroll
        for (int i = 0; i < 4; ++i) {
            int r = m0 + wm * (FM * 16) + fm * 16 + g * 4 + i;
            if (!GROUPED || r < mEnd) {
#pragma unroll
                for (int fn = 0; fn < 4; ++fn) {
                    float v = acc[fm][fn][i] + bv[fn];
                    if (LEAKY) v = v > 0.f ? v : 0.01f * v;
                    size_t off = (size_t)r * ND + n0 + wn * 64 + fn * 16 + li;
                    if (OUT_BF16)
                        ((__hip_bfloat16*)Cout)[off] = __float2bfloat16(v);
                    else
                        ((float*)Cout)[off] = v;
                }
            }
        }
}

// ---- named wrappers (distinct rocprof rows) ----
__global__ __launch_bounds__(256) void gemm_g1(const __hip_bfloat16* A, const __hip_bfloat16* Bt,
                                               const float* bias, void* C) {
    __shared__ __align__(16) __hip_bfloat16 smem[3 * (128 * 32 + 128 * 32)];
    gemm_body<128, L_DIM, H_DIM, false, true, true>(smem, A, Bt, bias, C, nullptr, nullptr);
}
__global__ __launch_bounds__(256) void gemm_g2(const __hip_bfloat16* A, const __hip_bfloat16* Bt,
                                               const float* bias, void* C) {
    __shared__ __align__(16) __hip_bfloat16 smem[3 * (64 * 32 + 128 * 32)];
    gemm_body<64, H_DIM, E_DIM, false, true, true>(smem, A, Bt, bias, C, nullptr, nullptr);
}
__global__ __launch_bounds__(256) void gemm_g4(const __hip_bfloat16* A, const __hip_bfloat16* Bt,
                                               const float* bias, void* C,
                                               const int* seg, const int* tp) {
    __shared__ __align__(16) __hip_bfloat16 smem[3 * (128 * 32 + 128 * 32)];
    gemm_body<128, H_DIM, L_DIM, true, false, false>(smem, A, Bt, bias, C, seg, tp);
}

// ---------------- G3: single-shot K=128 grouped GEMM ----------------
// Stage the WHOLE A(128x128) + B(128x128) panel (64 KB), one vmcnt(0)+barrier,
// then 64 MFMA with no further barriers. z is L2-resident; 2 blocks/CU.
__global__ __launch_bounds__(256) void gemm_g3(const __hip_bfloat16* __restrict__ A,
                                               const __hip_bfloat16* __restrict__ Bt,
                                               const float* __restrict__ bias,
                                               __hip_bfloat16* __restrict__ Cout,
                                               const int* __restrict__ seg,
                                               const int* __restrict__ tp) {
    constexpr int KD = E_DIM;   // 128
    constexpr int ND = H_DIM;   // 1024
    constexpr int NNT = ND / 128;
    constexpr int NMT = B_ROWS / 128 + K_EXP;
    constexpr int TOT = NMT * NNT;   // 2112
    static_assert(TOT % 8 == 0, "XCD chunking");
    constexpr int SLOT = 2 * 128 * 32;  // per-K-tile A+B
    __shared__ __align__(16) __hip_bfloat16 smem[4 * SLOT];  // 64 KB

    const int id = blockIdx.x;
    const int wg = (id & 7) * (TOT / 8) + (id >> 3);
    const int mt = wg / NNT, nt = wg % NNT;
    const int n0 = nt << 7;
    if (mt >= tp[K_EXP]) return;
    int e = 0;
    while (mt >= tp[e + 1]) ++e;
    const int m0 = seg[e] + ((mt - tp[e]) << 7);
    const int mEnd = seg[e + 1];
    const __hip_bfloat16* Bp = Bt + (size_t)e * KD * ND;
    const float* bp = bias + (size_t)e * ND;

    const int t = threadIdx.x, w = t >> 6, l = t & 63;
    const int wm = w >> 1, wn = w & 1, g = l >> 4, li = l & 15;
    const int q0 = 2 * w, r0 = l >> 2, s0 = l & 3;

    // stage all 4 K-tiles (16 gloads/thread)
#pragma unroll
    for (int kt = 0; kt < 4; ++kt) {
#pragma unroll
        for (int qi = 0; qi < 2; ++qi) {
            int q = q0 + qi, r = q * 16 + r0;
            int ksg = s0 ^ ((r >> 1) & 3);
            int rowg = min(m0 + r, B_ROWS - 1);
            gload16(A + (size_t)rowg * KD + kt * 32 + ksg * 8,
                    &smem[kt * SLOT + q * 512]);
        }
#pragma unroll
        for (int qi = 0; qi < 2; ++qi) {
            int q = q0 + qi, r = q * 16 + r0;
            int ksg = s0 ^ ((r >> 1) & 3);
            gload16(Bp + (size_t)(n0 + r) * KD + kt * 32 + ksg * 8,
                    &smem[kt * SLOT + 4096 + q * 512]);
        }
    }
    asm volatile("s_waitcnt vmcnt(0)\ns_barrier" ::: "memory");

    f32x4 acc[4][4];
#pragma unroll
    for (int i = 0; i < 4; ++i)
#pragma unroll
        for (int j = 0; j < 4; ++j) acc[i][j] = (f32x4){0.f, 0.f, 0.f, 0.f};

#pragma unroll
    for (int kt = 0; kt < 4; ++kt) {
        bf16x8 af[4], bfr[4];
#pragma unroll
        for (int fm = 0; fm < 4; ++fm) {
            int rr = wm * 64 + fm * 16 + li;
            int ss = g ^ ((rr >> 1) & 3);
            af[fm] = *(const bf16x8*)&smem[kt * SLOT + rr * 32 + ss * 8];
        }
#pragma unroll
        for (int fn = 0; fn < 4; ++fn) {
            int cc = wn * 64 + fn * 16 + li;
            int ss = g ^ ((cc >> 1) & 3);
            bfr[fn] = *(const bf16x8*)&smem[kt * SLOT + 4096 + cc * 32 + ss * 8];
        }
        __builtin_amdgcn_s_setprio(1);
#pragma unroll
        for (int fm = 0; fm < 4; ++fm)
#pragma unroll
            for (int fn = 0; fn < 4; ++fn)
                acc[fm][fn] = __builtin_amdgcn_mfma_f32_16x16x32_bf16(
                    af[fm], bfr[fn], acc[fm][fn], 0, 0, 0);
        __builtin_amdgcn_s_setprio(0);
    }

    float bv[4];
#pragma unroll
    for (int fn = 0; fn < 4; ++fn) bv[fn] = bp[n0 + wn * 64 + fn * 16 + li];
#pragma unroll
    for (int fm = 0; fm < 4; ++fm)
#pragma unroll
        for (int i = 0; i < 4; ++i) {
            int r = m0 + wm * 64 + fm * 16 + g * 4 + i;
            if (r < mEnd) {
#pragma unroll
                for (int fn = 0; fn < 4; ++fn) {
                    float v = acc[fm][fn][i] + bv[fn];
                    v = v > 0.f ? v : 0.01f * v;
                    Cout[(size_t)r * ND + n0 + wn * 64 + fn * 16 + li] = __float2bfloat16(v);
                }
            }
        }
}

extern "C" void kernel_launch(void* const* d_in, const int* in_sizes, int n_in,
                              void* d_out, int out_size, void* d_ws, size_t ws_size,
                              hipStream_t stream) {
    (void)in_sizes; (void)n_in; (void)out_size; (void)ws_size;
    const float* x   = (const float*)d_in[0];
    const float* We1 = (const float*)d_in[1];
    const float* be1 = (const float*)d_in[2];
    const float* We2 = (const float*)d_in[3];
    const float* be2 = (const float*)d_in[4];
    const float* Wd1 = (const float*)d_in[5];
    const float* bd1 = (const float*)d_in[6];
    const float* Wd2 = (const float*)d_in[7];
    const float* bd2 = (const float*)d_in[8];
    float* out = (float*)d_out;

    char* w = (char*)d_ws;
    auto alloc = [&](size_t bytes) {
        char* p = w;
        w += (bytes + 255) & ~(size_t)255;
        return p;
    };
    int* ids   = (int*)alloc((size_t)B_ROWS * 4);
    int* order = (int*)alloc((size_t)B_ROWS * 4);
    int* hist  = (int*)alloc((size_t)NBLK * K_EXP * 4);
    int* base  = (int*)alloc((size_t)NBLK * K_EXP * 4);
    int* seg   = (int*)alloc((K_EXP + 1) * 4);
    int* tp    = (int*)alloc((K_EXP + 1) * 4);
    __hip_bfloat16* xs   = (__hip_bfloat16*)alloc((size_t)B_ROWS * L_DIM * 2);
    __hip_bfloat16* hbuf = (__hip_bfloat16*)alloc((size_t)B_ROWS * H_DIM * 2);
    __hip_bfloat16* zbuf = (__hip_bfloat16*)alloc((size_t)B_ROWS * E_DIM * 2);
    __hip_bfloat16* Wt1  = (__hip_bfloat16*)alloc((size_t)L_DIM * H_DIM * 2);
    __hip_bfloat16* Wt2  = (__hip_bfloat16*)alloc((size_t)H_DIM * E_DIM * 2);
    __hip_bfloat16* Wd1t = (__hip_bfloat16*)alloc((size_t)K_EXP * E_DIM * H_DIM * 2);
    __hip_bfloat16* Wd2t = (__hip_bfloat16*)alloc((size_t)K_EXP * H_DIM * L_DIM * 2);

    k_ids_hist<<<NBLK, 256, 0, stream>>>(x, ids, hist);
    k_scan<<<1, 64, 0, stream>>>(hist, base, seg, tp);
    k_order<<<NBLK, 256, 0, stream>>>(ids, base, order);
    k_gather<<<(B_ROWS * (L_DIM / 4)) / 256, 256, 0, stream>>>(x, order, xs);
    k_wtrans<<<5760, 256, 0, stream>>>(We1, We2, Wd1, Wd2, Wt1, Wt2, Wd1t, Wd2t);

    // G1: h = leaky(xs @ We1 + be1)      [32768,512]@[512,1024]
    gemm_g1<<<(B_ROWS / 128) * (H_DIM / 128), 256, 0, stream>>>(xs, Wt1, be1, hbuf);
    // G2: z = leaky(h @ We2 + be2)       [32768,1024]@[1024,128]
    gemm_g2<<<(B_ROWS / 64) * (E_DIM / 128), 256, 0, stream>>>(hbuf, Wt2, be2, zbuf);
    // G3: hd = leaky(z @ Wd1[e] + bd1[e])  grouped, single-shot K=128
    gemm_g3<<<(B_ROWS / 128 + K_EXP) * (H_DIM / 128), 256, 0, stream>>>(zbuf, Wd1t, bd1, hbuf, seg, tp);
    // G4: out = hd @ Wd2[e] + bd2[e]     grouped, fp32 out
    gemm_g4<<<(B_ROWS / 128 + K_EXP) * (L_DIM / 128), 256, 0, stream>>>(hbuf, Wd2t, bd2, out, seg, tp);
}